// Round 8
// baseline (192.063 us; speedup 1.0000x reference)
//
#include <hip/hip_runtime.h>
#include <hip/hip_bf16.h>

// ALiBi causal attention, B=2 T=2048 C=1024 H=16 D=64. Inputs fp32, output fp32.
// Round 8: attn re-partitioned for occupancy: 64 q-rows/block (2 waves, 128
// thr), 128-kv stages, grid 32x32 = 1024 blocks -> 4 blocks/CU (was 2).
// Per-wave math identical to round 7 (32x32x16 MFMA, permuted K staging,
// static-max softmax). GEMMs/cvt unchanged.

typedef _Float16 f16;
typedef f16 f16x2 __attribute__((ext_vector_type(2)));
typedef f16 f16x4 __attribute__((ext_vector_type(4)));
typedef f16 f16x8 __attribute__((ext_vector_type(8)));
typedef float f32x4 __attribute__((ext_vector_type(4)));
typedef float f32x16 __attribute__((ext_vector_type(16)));

#define LOG2E 1.4426950408889634f
#define LDA 72   // attn K-tile stride (halves): 144B rows, b128-aligned
#define LDV 136  // attn V^T-tile stride (halves): 272B rows, b128-aligned

typedef const __attribute__((address_space(1))) unsigned int* gas1;
typedef __attribute__((address_space(3))) unsigned int* las3;
__device__ __forceinline__ void gload16(const f16* g, f16* l) {
  __builtin_amdgcn_global_load_lds((gas1)g, (las3)l, 16, 0, 0);
}

__device__ __forceinline__ f16x4 pk4(f32x4 v) {
  f16x2 a = __builtin_bit_cast(f16x2, __builtin_amdgcn_cvt_pkrtz(v[0], v[1]));
  f16x2 b = __builtin_bit_cast(f16x2, __builtin_amdgcn_cvt_pkrtz(v[2], v[3]));
  f16x4 r; r[0] = a[0]; r[1] = a[1]; r[2] = b[0]; r[3] = b[1];
  return r;
}
// pack P fragment p from ev[16]: slots 0..3 = ev[4p..], 4..7 = ev[8+4p..]
__device__ __forceinline__ f16x8 mkp(const float* e, int p) {
  f16x2 a = __builtin_bit_cast(f16x2, __builtin_amdgcn_cvt_pkrtz(e[4*p+0], e[4*p+1]));
  f16x2 b = __builtin_bit_cast(f16x2, __builtin_amdgcn_cvt_pkrtz(e[4*p+2], e[4*p+3]));
  f16x2 c = __builtin_bit_cast(f16x2, __builtin_amdgcn_cvt_pkrtz(e[8+4*p+0], e[8+4*p+1]));
  f16x2 d = __builtin_bit_cast(f16x2, __builtin_amdgcn_cvt_pkrtz(e[8+4*p+2], e[8+4*p+3]));
  f16x8 r;
  r[0]=a[0]; r[1]=a[1]; r[2]=b[0]; r[3]=b[1];
  r[4]=c[0]; r[5]=c[1]; r[6]=d[0]; r[7]=d[1];
  return r;
}

// ----------------------------------------------------------------- cvt kernel
__global__ __launch_bounds__(256) void cvt_f32_f16(
    const float* __restrict__ x, const float* __restrict__ wq,
    const float* __restrict__ wk, const float* __restrict__ wv,
    const float* __restrict__ wo,
    f16* __restrict__ dx, f16* __restrict__ dwq, f16* __restrict__ dwk,
    f16* __restrict__ dwv, f16* __restrict__ dwo) {
  const float* src; f16* dst; int n;
  switch (blockIdx.y) {
    case 0:  src = x;  dst = dx;  n = 4194304; break;
    case 1:  src = wq; dst = dwq; n = 1048576; break;
    case 2:  src = wk; dst = dwk; n = 1048576; break;
    case 3:  src = wv; dst = dwv; n = 1048576; break;
    default: src = wo; dst = dwo; n = 1048576; break;
  }
  int i = (blockIdx.x * 256 + (int)threadIdx.x) * 8;
  if (i >= n) return;
  f32x4 a = *(const f32x4*)(src + i);
  f32x4 b = *(const f32x4*)(src + i + 4);
  f16x8 o;
  f16x4 lo4 = pk4(a), hi4 = pk4(b);
#pragma unroll
  for (int j = 0; j < 4; j++) { o[j] = lo4[j]; o[j + 4] = hi4[j]; }
  *(f16x8*)(dst + i) = o;
}

// ------------------------------------------------- GEMM core (m97 structure)
__device__ __forceinline__ void gemm_core(const f16* __restrict__ A,
                                          const f16* __restrict__ W,
                                          int m0, int n0,
                                          f16* lA, f16* lW,
                                          f32x4 acc[4][4]) {
  const int tid = threadIdx.x;
  const int lane = tid & 63, w = tid >> 6;
  const int wm = w & 1, wn = w >> 1;
  const int q = lane & 15, quad = lane >> 4;
  const int lrow = lane >> 2, lcol = (lane & 3) * 8;

  for (int kt = 0; kt < 1024; kt += 32) {
    __syncthreads();
#pragma unroll
    for (int t = 0; t < 2; t++) {
      const int slot = t * 4 + w;
      const int row = slot * 16 + lrow;
      gload16(A + (m0 + row) * 1024 + kt + lcol, lA + slot * 512);
      gload16(W + (n0 + row) * 1024 + kt + lcol, lW + slot * 512);
    }
    __syncthreads();
    f16x8 aF[4], bF[4];
#pragma unroll
    for (int mt = 0; mt < 4; mt++)
      aF[mt] = *(const f16x8*)(lA + (wm * 64 + mt * 16 + q) * 32 + quad * 8);
#pragma unroll
    for (int nt = 0; nt < 4; nt++)
      bF[nt] = *(const f16x8*)(lW + (wn * 64 + nt * 16 + q) * 32 + quad * 8);
#pragma unroll
    for (int mt = 0; mt < 4; mt++)
#pragma unroll
      for (int nt = 0; nt < 4; nt++)
        acc[mt][nt] = __builtin_amdgcn_mfma_f32_16x16x32_f16(aF[mt], bF[nt], acc[mt][nt], 0, 0, 0);
  }
}

// ------------------------------------------------------------ QKV projection
__global__ __launch_bounds__(256) void qkv_proj(
    const f16* __restrict__ x16, const f16* __restrict__ wq16,
    const f16* __restrict__ wk16, const f16* __restrict__ wv16,
    f16* __restrict__ qb, f16* __restrict__ kb, f16* __restrict__ vb,
    float qscale) {
  __shared__ __align__(16) f16 lA[128 * 32];
  __shared__ __align__(16) f16 lW[128 * 32];
  const int m0 = blockIdx.x * 128, n0 = blockIdx.y * 128;
  const int z = blockIdx.z;
  const f16* W = (z == 0) ? wq16 : (z == 1) ? wk16 : wv16;
  f16* out = (z == 0) ? qb : (z == 1) ? kb : vb;
  const float scale = (z == 0) ? qscale : 1.0f;

  f32x4 acc[4][4];
  const f32x4 zero = {0.f, 0.f, 0.f, 0.f};
#pragma unroll
  for (int i = 0; i < 4; i++)
#pragma unroll
    for (int j = 0; j < 4; j++) acc[i][j] = zero;
  gemm_core(x16, W, m0, n0, lA, lW, acc);

  const int tid = threadIdx.x, lane = tid & 63, w = tid >> 6;
  const int wm = w & 1, wn = w >> 1, q = lane & 15, quad = lane >> 4;
#pragma unroll
  for (int mt = 0; mt < 4; mt++)
#pragma unroll
    for (int nt = 0; nt < 4; nt++) {
      int n = n0 + wn * 64 + nt * 16 + q;
      int h = n >> 6, d = n & 63;
#pragma unroll
      for (int r = 0; r < 4; r++) {
        int mm = m0 + wm * 64 + mt * 16 + quad * 4 + r;
        int bb = mm >> 11, tl = mm & 2047;
        out[((bb * 16 + h) * 2048 + tl) * 64 + d] = (f16)(acc[mt][nt][r] * scale);
      }
    }
}

// --------------------------------------------------------------- attention
// grid (32 bh, 32 tiles): qi = 31 - y (long first). 128 threads = 2 waves;
// wave w owns 32 Q rows of the 64-row tile. 128-kv stages, register prefetch.
// All MFMA 32x32x16; K rows staged permuted so QK^T C-regs feed PV B-operand.
__global__ __launch_bounds__(128, 2) void attn(
    const f16* __restrict__ qB, const f16* __restrict__ kB,
    const f16* __restrict__ vB, f16* __restrict__ att) {
  __shared__ __align__(16) f16 lK[128 * LDA];  // [kv(perm)][d]  18432 B
  __shared__ __align__(16) f16 lV[64 * LDV];   // [d][kv]        17408 B
  const int tid = threadIdx.x, lane = tid & 63, w = tid >> 6;
  const int n5 = lane & 31, hh = lane >> 5;
  const int bh = blockIdx.x, qi = 31 - (int)blockIdx.y;
  const int b = bh >> 4, h = bh & 15;
  const int q0 = qi * 64;
  const f16* qP = qB + (bh * 2048) * 64;
  const f16* kP = kB + (bh * 2048) * 64;
  const f16* vP = vB + (bh * 2048) * 64;

  const float slope2 = __builtin_amdgcn_exp2f(-0.5f * (float)(h + 1)) * LOG2E;
  const int qg = q0 + w * 32 + n5;              // this lane's q row (C col)
  const int qlast = q0 + w * 32 + 31;           // wave's last q row
  const int wdiag = ((q0 + w * 32) >> 6) << 6;  // 64-half holding wave's diag

  f16x8 qF[4];  // B-operand: B[k = ks*16 + hh*8 + j][n = qg]
#pragma unroll
  for (int ks = 0; ks < 4; ks++)
    qF[ks] = *(const f16x8*)(qP + qg * 64 + ks * 16 + hh * 8);

  f32x16 cinit, ot0, ot1;
#pragma unroll
  for (int i = 0; i < 16; i++) { cinit[i] = -8.0f; ot0[i] = 0.f; ot1[i] = 0.f; }
  float lsum = 0.0f;

  // K staging: thread -> row kr (permuted within 32-tile), 8 col segs.
  const int kr = tid;
  const int pp = kr & 31;
  const int mperm = (pp & 3) + 16 * ((pp >> 2) & 1) + 4 * ((pp >> 3) & 1) + 8 * ((pp >> 4) & 1);
  const int lkr = (kr & 96) + mperm;
  // V staging: thread -> 4 kv rows (va..va+3) x 16 d (vd..vd+15); transpose
  // to lV[d][kv] via b64 writes.
  const int va = (tid & 31) * 4, vd = (tid >> 5) * 16;

  f16x8 kreg[8], vreg[4][2];
#pragma unroll
  for (int j = 0; j < 8; j++)
    kreg[j] = *(const f16x8*)(kP + kr * 64 + j * 8);
#pragma unroll
  for (int r = 0; r < 4; r++) {
    vreg[r][0] = *(const f16x8*)(vP + (va + r) * 64 + vd);
    vreg[r][1] = *(const f16x8*)(vP + (va + r) * 64 + vd + 8);
  }

  const int nstage = (qi >> 1) + 1;  // ceil((qi+1)/2)
  for (int stg = 0; stg < nstage; stg++) {
    const int kv0 = stg << 7;
    __syncthreads();
#pragma unroll
    for (int j = 0; j < 8; j++)
      *(f16x8*)(lK + lkr * LDA + j * 8) = kreg[j];
#pragma unroll
    for (int s2 = 0; s2 < 2; s2++)
#pragma unroll
      for (int j = 0; j < 8; j++) {
        f16x4 t;
        t[0] = vreg[0][s2][j]; t[1] = vreg[1][s2][j];
        t[2] = vreg[2][s2][j]; t[3] = vreg[3][s2][j];
        *(f16x4*)(lV + (vd + s2 * 8 + j) * LDV + va) = t;
      }
    __syncthreads();
    if (stg + 1 < nstage) {
      const int kn = kv0 + 128;
#pragma unroll
      for (int j = 0; j < 8; j++)
        kreg[j] = *(const f16x8*)(kP + (kn + kr) * 64 + j * 8);
#pragma unroll
      for (int r = 0; r < 4; r++) {
        vreg[r][0] = *(const f16x8*)(vP + (kn + va + r) * 64 + vd);
        vreg[r][1] = *(const f16x8*)(vP + (kn + va + r) * 64 + vd + 8);
      }
    }
#pragma unroll
    for (int half = 0; half < 2; half++) {
      const int kvh = kv0 + half * 64;
      if (kvh > wdiag) break;                    // wave-uniform
      const bool act1 = (kvh + 32 <= qlast);     // upper 32-kv tile live?
      const bool needmask = (kvh == wdiag);
      // S^T = K.Q^T, C-init = -8 (static max)
      f32x16 s0 = cinit, s1 = cinit;
#pragma unroll
      for (int ks = 0; ks < 4; ks++) {
        f16x8 kf = *(const f16x8*)(lK + (half * 64 + n5) * LDA + ks * 16 + hh * 8);
        s0 = __builtin_amdgcn_mfma_f32_32x32x16_f16(kf, qF[ks], s0, 0, 0, 0);
      }
      if (act1) {
#pragma unroll
        for (int ks = 0; ks < 4; ks++) {
          f16x8 kf = *(const f16x8*)(lK + (half * 64 + 32 + n5) * LDA + ks * 16 + hh * 8);
          s1 = __builtin_amdgcn_mfma_f32_32x32x16_f16(kf, qF[ks], s1, 0, 0, 0);
        }
      }
      // bias + mask + exp2. Element (reg=t+4u, hh) = physical kv offset
      // CR + 8*hh within its 32-tile, CR = 16*(u&1) + 4*(u>>1) + t.
      f16x8 pf00, pf01, pf10, pf11;
      {
        const int dQ = qg - kvh - 8 * hh;
        const float base0 = -slope2 * (float)dQ;
        float ev[16];
#pragma unroll
        for (int u = 0; u < 4; u++)
#pragma unroll
          for (int t = 0; t < 4; t++) {
            const int reg = t + 4 * u;
            const int CR = 16 * (u & 1) + 4 * (u >> 1) + t;
            float val = s0[reg] + fmaf(slope2, (float)CR, base0);
            if (needmask) val = (dQ >= CR) ? val : -1e30f;
            ev[reg] = __builtin_amdgcn_exp2f(val);
          }
        lsum += (((ev[0]+ev[1])+(ev[2]+ev[3])) + ((ev[4]+ev[5])+(ev[6]+ev[7])))
              + (((ev[8]+ev[9])+(ev[10]+ev[11])) + ((ev[12]+ev[13])+(ev[14]+ev[15])));
        pf00 = mkp(ev, 0); pf01 = mkp(ev, 1);
        if (act1) {
          const int dQ1 = dQ - 32;
          const float base1 = -slope2 * (float)dQ1;
          float ev1[16];
#pragma unroll
          for (int u = 0; u < 4; u++)
#pragma unroll
            for (int t = 0; t < 4; t++) {
              const int reg = t + 4 * u;
              const int CR = 16 * (u & 1) + 4 * (u >> 1) + t;
              float val = s1[reg] + fmaf(slope2, (float)CR, base1);
              if (needmask) val = (dQ1 >= CR) ? val : -1e30f;
              ev1[reg] = __builtin_amdgcn_exp2f(val);
            }
          lsum += (((ev1[0]+ev1[1])+(ev1[2]+ev1[3])) + ((ev1[4]+ev1[5])+(ev1[6]+ev1[7])))
                + (((ev1[8]+ev1[9])+(ev1[10]+ev1[11])) + ((ev1[12]+ev1[13])+(ev1[14]+ev1[15])));
          pf10 = mkp(ev1, 0); pf11 = mkp(ev1, 1);
        }
      }
      // O^T += V^T . P^T  (A = V^T b128 reads, contiguous physical kv)
#pragma unroll
      for (int p = 0; p < 2; p++) {
        f16x8 vf0 = *(const f16x8*)(lV + n5 * LDV + half * 64 + p * 16 + hh * 8);
        f16x8 vf1 = *(const f16x8*)(lV + (32 + n5) * LDV + half * 64 + p * 16 + hh * 8);
        f16x8 pf = p ? pf01 : pf00;
        ot0 = __builtin_amdgcn_mfma_f32_32x32x16_f16(vf0, pf, ot0, 0, 0, 0);
        ot1 = __builtin_amdgcn_mfma_f32_32x32x16_f16(vf1, pf, ot1, 0, 0, 0);
      }
      if (act1) {
#pragma unroll
        for (int p = 0; p < 2; p++) {
          f16x8 vf0 = *(const f16x8*)(lV + n5 * LDV + half * 64 + 32 + p * 16 + hh * 8);
          f16x8 vf1 = *(const f16x8*)(lV + (32 + n5) * LDV + half * 64 + 32 + p * 16 + hh * 8);
          f16x8 pf = p ? pf11 : pf10;
          ot0 = __builtin_amdgcn_mfma_f32_32x32x16_f16(vf0, pf, ot0, 0, 0, 0);
          ot1 = __builtin_amdgcn_mfma_f32_32x32x16_f16(vf1, pf, ot1, 0, 0, 0);
        }
      }
    }
  }

  // l per q-col lives split across hh halves only
  lsum += __shfl_xor(lsum, 32);
  const float inv = 1.0f / lsum;

  // epilogue: O^T regs -> LDS [q][d] -> coalesced f16x8 stores
  __syncthreads();
  f16* OT = lK + w * (32 * LDA);
#pragma unroll
  for (int dt = 0; dt < 2; dt++)
#pragma unroll
    for (int u = 0; u < 4; u++) {
      f16x4 o4;
#pragma unroll
      for (int t = 0; t < 4; t++) {
        float v = (dt ? ot1[t + 4 * u] : ot0[t + 4 * u]) * inv;
        o4[t] = (f16)v;
      }
      // d = dt*32 + 8u + 4hh + t
      *(f16x4*)(OT + n5 * LDA + dt * 32 + 8 * u + 4 * hh) = o4;
    }
  __syncthreads();
  const int row = lane >> 1, hr = lane & 1;
  const f16* OR = lK + w * (32 * LDA) + row * LDA + hr * 32;
  f16* dst = att + (b * 2048 + q0 + w * 32 + row) * 1024 + h * 64 + hr * 32;
#pragma unroll
  for (int j = 0; j < 4; j++)
    *(f16x8*)(dst + j * 8) = *(const f16x8*)(OR + j * 8);
}

// ---------------------------------------------------------- output projection
__global__ __launch_bounds__(256) void out_proj(
    const f16* __restrict__ att, const f16* __restrict__ wo16,
    float* __restrict__ out) {
  __shared__ __align__(16) f16 lA[128 * 32];
  __shared__ __align__(16) f16 lW[128 * 32];
  const int m0 = blockIdx.x * 128, n0 = blockIdx.y * 128;
  f32x4 acc[4][4];
  const f32x4 zero = {0.f, 0.f, 0.f, 0.f};
#pragma unroll
  for (int i = 0; i < 4; i++)
#pragma unroll
    for (int j = 0; j < 4; j++) acc[i][j] = zero;
  gemm_core(att, wo16, m0, n0, lA, lW, acc);

  const int tid = threadIdx.x, lane = tid & 63, w = tid >> 6;
  const int wm = w & 1, wn = w >> 1, q = lane & 15, quad = lane >> 4;
#pragma unroll
  for (int mt = 0; mt < 4; mt++)
#pragma unroll
    for (int nt = 0; nt < 4; nt++) {
      int n = n0 + wn * 64 + nt * 16 + q;
#pragma unroll
      for (int r = 0; r < 4; r++) {
        int mm = m0 + wm * 64 + mt * 16 + quad * 4 + r;
        out[mm * 1024 + n] = acc[mt][nt][r];
      }
    }
}

// ------------------------------------------------------------------- launch
extern "C" void kernel_launch(void* const* d_in, const int* in_sizes, int n_in,
                              void* d_out, int out_size, void* d_ws, size_t ws_size,
                              hipStream_t stream) {
  const float* x  = (const float*)d_in[0];
  const float* Wq = (const float*)d_in[1];
  const float* Wk = (const float*)d_in[2];
  const float* Wv = (const float*)d_in[3];
  const float* Wo = (const float*)d_in[4];
  char* ws = (char*)d_ws;
  const size_t MB = 1024 * 1024;
  f16* x16  = (f16*)(ws);             // 8 MB; dead after qkv -> reused as att
  f16* qb   = (f16*)(ws + 8 * MB);    // (B,H,T,D) f16, 8 MB each
  f16* kb   = (f16*)(ws + 16 * MB);
  f16* vb   = (f16*)(ws + 24 * MB);
  f16* wq16 = (f16*)(ws + 32 * MB);   // 2 MB each
  f16* wk16 = (f16*)(ws + 34 * MB);
  f16* wv16 = (f16*)(ws + 36 * MB);
  f16* wo16 = (f16*)(ws + 38 * MB);   // total 40 MB
  f16* att  = x16;                    // overlay

  cvt_f32_f16<<<dim3(2048, 5), 256, 0, stream>>>(x, Wq, Wk, Wv, Wo,
                                                 x16, wq16, wk16, wv16, wo16);
  qkv_proj<<<dim3(32, 8, 3), 256, 0, stream>>>(x16, wq16, wk16, wv16,
                                               qb, kb, vb, 0.125f * LOG2E);
  attn<<<dim3(32, 32), 128, 0, stream>>>(qb, kb, vb, att);
  out_proj<<<dim3(32, 8), 256, 0, stream>>>(att, wo16, (float*)d_out);
}

// Round 9
// 186.025 us; speedup vs baseline: 1.0325x; 1.0325x over previous
//
#include <hip/hip_runtime.h>
#include <hip/hip_bf16.h>

// ALiBi causal attention, B=2 T=2048 C=1024 H=16 D=64. Inputs fp32, output fp32.
// Round 9: attn reverted to round-7 version (52us known-good; r8's 128-thr
// repartition regressed -- LDS/block unchanged => waves/CU unchanged, staging
// doubled). GEMMs rewritten attn-style: register-prefetch + ds_write dbuf LDS,
// ONE barrier per 32-K round (was 2), padded LDK=40 (2-way conflicts max).

typedef _Float16 f16;
typedef f16 f16x2 __attribute__((ext_vector_type(2)));
typedef f16 f16x4 __attribute__((ext_vector_type(4)));
typedef f16 f16x8 __attribute__((ext_vector_type(8)));
typedef float f32x4 __attribute__((ext_vector_type(4)));
typedef float f32x16 __attribute__((ext_vector_type(16)));

#define LOG2E 1.4426950408889634f
#define LDK 40   // GEMM LDS stride (halves): 80B rows; write/read <=2-way banks
#define LDA 72   // attn K-tile stride (halves): 144B rows, b128-aligned
#define LDV 136  // attn V^T-tile stride (halves): 272B rows, b128-aligned

__device__ __forceinline__ f16x4 pk4(f32x4 v) {
  f16x2 a = __builtin_bit_cast(f16x2, __builtin_amdgcn_cvt_pkrtz(v[0], v[1]));
  f16x2 b = __builtin_bit_cast(f16x2, __builtin_amdgcn_cvt_pkrtz(v[2], v[3]));
  f16x4 r; r[0] = a[0]; r[1] = a[1]; r[2] = b[0]; r[3] = b[1];
  return r;
}
// pack P fragment p from ev[16]: slots 0..3 = ev[4p..], 4..7 = ev[8+4p..]
__device__ __forceinline__ f16x8 mkp(const float* e, int p) {
  f16x2 a = __builtin_bit_cast(f16x2, __builtin_amdgcn_cvt_pkrtz(e[4*p+0], e[4*p+1]));
  f16x2 b = __builtin_bit_cast(f16x2, __builtin_amdgcn_cvt_pkrtz(e[4*p+2], e[4*p+3]));
  f16x2 c = __builtin_bit_cast(f16x2, __builtin_amdgcn_cvt_pkrtz(e[8+4*p+0], e[8+4*p+1]));
  f16x2 d = __builtin_bit_cast(f16x2, __builtin_amdgcn_cvt_pkrtz(e[8+4*p+2], e[8+4*p+3]));
  f16x8 r;
  r[0]=a[0]; r[1]=a[1]; r[2]=b[0]; r[3]=b[1];
  r[4]=c[0]; r[5]=c[1]; r[6]=d[0]; r[7]=d[1];
  return r;
}

// ----------------------------------------------------------------- cvt kernel
__global__ __launch_bounds__(256) void cvt_f32_f16(
    const float* __restrict__ x, const float* __restrict__ wq,
    const float* __restrict__ wk, const float* __restrict__ wv,
    const float* __restrict__ wo,
    f16* __restrict__ dx, f16* __restrict__ dwq, f16* __restrict__ dwk,
    f16* __restrict__ dwv, f16* __restrict__ dwo) {
  const float* src; f16* dst; int n;
  switch (blockIdx.y) {
    case 0:  src = x;  dst = dx;  n = 4194304; break;
    case 1:  src = wq; dst = dwq; n = 1048576; break;
    case 2:  src = wk; dst = dwk; n = 1048576; break;
    case 3:  src = wv; dst = dwv; n = 1048576; break;
    default: src = wo; dst = dwo; n = 1048576; break;
  }
  int i = (blockIdx.x * 256 + (int)threadIdx.x) * 8;
  if (i >= n) return;
  f32x4 a = *(const f32x4*)(src + i);
  f32x4 b = *(const f32x4*)(src + i + 4);
  f16x8 o;
  f16x4 lo4 = pk4(a), hi4 = pk4(b);
#pragma unroll
  for (int j = 0; j < 4; j++) { o[j] = lo4[j]; o[j + 4] = hi4[j]; }
  *(f16x8*)(dst + i) = o;
}

// ---------------------------------------------- GEMM core (dbuf, 1 barrier)
// C[m][n] = sum_k A[m][k]*W[n][k]; A,W f16 row-major, K=1024. 128x128 tile,
// BK=32, 4 waves 2x2 (wave = 64x64 = 4x4 x32-MFMA tiles). Staging: global->
// VGPR prefetch + ds_write into double-buffered padded LDS; one barrier/round
// (write buf p; prefetch r+1; barrier; compute buf p). Loads for r+1 stay in
// flight under round-r MFMA (barriers don't drain global->VGPR loads).
__device__ __forceinline__ void gemm_core(const f16* __restrict__ A,
                                          const f16* __restrict__ W,
                                          int m0, int n0,
                                          f16* lA, f16* lW,  // each 2*128*LDK
                                          f32x4 acc[4][4]) {
  const int tid = threadIdx.x;
  const int lane = tid & 63, w = tid >> 6;
  const int wm = w & 1, wn = w >> 1;
  const int q = lane & 15, quad = lane >> 4;
  const int r0 = tid >> 2, c0 = (tid & 3) * 8;  // staging: rows {r0, r0+64}

  const f16* Ap = A + (m0 + r0) * 1024 + c0;
  const f16* Wp = W + (n0 + r0) * 1024 + c0;
  f16x8 a0 = *(const f16x8*)(Ap);
  f16x8 a1 = *(const f16x8*)(Ap + 64 * 1024);
  f16x8 w0 = *(const f16x8*)(Wp);
  f16x8 w1 = *(const f16x8*)(Wp + 64 * 1024);

#pragma unroll 2
  for (int r = 0; r < 32; r++) {
    const int p = r & 1;
    f16* dA = lA + p * (128 * LDK);
    f16* dW = lW + p * (128 * LDK);
    *(f16x8*)(dA + r0 * LDK + c0) = a0;
    *(f16x8*)(dA + (64 + r0) * LDK + c0) = a1;
    *(f16x8*)(dW + r0 * LDK + c0) = w0;
    *(f16x8*)(dW + (64 + r0) * LDK + c0) = w1;
    if (r + 1 < 32) {
      const int kn = (r + 1) * 32;
      a0 = *(const f16x8*)(Ap + kn);
      a1 = *(const f16x8*)(Ap + 64 * 1024 + kn);
      w0 = *(const f16x8*)(Wp + kn);
      w1 = *(const f16x8*)(Wp + 64 * 1024 + kn);
    }
    __syncthreads();  // buf p writes visible; prior buf reads already ordered
    f16x8 aF[4], bF[4];
#pragma unroll
    for (int mt = 0; mt < 4; mt++)
      aF[mt] = *(const f16x8*)(dA + (wm * 64 + mt * 16 + q) * LDK + quad * 8);
#pragma unroll
    for (int nt = 0; nt < 4; nt++)
      bF[nt] = *(const f16x8*)(dW + (wn * 64 + nt * 16 + q) * LDK + quad * 8);
#pragma unroll
    for (int mt = 0; mt < 4; mt++)
#pragma unroll
      for (int nt = 0; nt < 4; nt++)
        acc[mt][nt] = __builtin_amdgcn_mfma_f32_16x16x32_f16(aF[mt], bF[nt], acc[mt][nt], 0, 0, 0);
  }
}

// ------------------------------------------------------------ QKV projection
__global__ __launch_bounds__(256) void qkv_proj(
    const f16* __restrict__ x16, const f16* __restrict__ wq16,
    const f16* __restrict__ wk16, const f16* __restrict__ wv16,
    f16* __restrict__ qb, f16* __restrict__ kb, f16* __restrict__ vb,
    float qscale) {
  __shared__ __align__(16) f16 lA[2 * 128 * LDK];
  __shared__ __align__(16) f16 lW[2 * 128 * LDK];
  const int m0 = blockIdx.x * 128, n0 = blockIdx.y * 128;
  const int z = blockIdx.z;
  const f16* W = (z == 0) ? wq16 : (z == 1) ? wk16 : wv16;
  f16* out = (z == 0) ? qb : (z == 1) ? kb : vb;
  const float scale = (z == 0) ? qscale : 1.0f;

  f32x4 acc[4][4];
  const f32x4 zero = {0.f, 0.f, 0.f, 0.f};
#pragma unroll
  for (int i = 0; i < 4; i++)
#pragma unroll
    for (int j = 0; j < 4; j++) acc[i][j] = zero;
  gemm_core(x16, W, m0, n0, lA, lW, acc);

  const int tid = threadIdx.x, lane = tid & 63, w = tid >> 6;
  const int wm = w & 1, wn = w >> 1, q = lane & 15, quad = lane >> 4;
#pragma unroll
  for (int mt = 0; mt < 4; mt++)
#pragma unroll
    for (int nt = 0; nt < 4; nt++) {
      int n = n0 + wn * 64 + nt * 16 + q;
      int h = n >> 6, d = n & 63;
#pragma unroll
      for (int r = 0; r < 4; r++) {
        int mm = m0 + wm * 64 + mt * 16 + quad * 4 + r;
        int bb = mm >> 11, tl = mm & 2047;
        out[((bb * 16 + h) * 2048 + tl) * 64 + d] = (f16)(acc[mt][nt][r] * scale);
      }
    }
}

// --------------------------------------------------------------- attention
// (round-7 version, verbatim: 52us measured) grid (32 bh, 16 tiles), 256 thr
// = 4 waves x 32 q rows. 128-kv stages, register prefetch, 32x32x16 MFMA,
// permuted K staging so QK^T C-regs feed PV B-operand, static-max softmax.
__global__ __launch_bounds__(256) void attn(
    const f16* __restrict__ qB, const f16* __restrict__ kB,
    const f16* __restrict__ vB, f16* __restrict__ att) {
  __shared__ __align__(16) f16 lK[128 * LDA];  // [kv(perm)][d]  18432 B
  __shared__ __align__(16) f16 lV[64 * LDV];   // [d][kv]        17408 B
  const int tid = threadIdx.x, lane = tid & 63, w = tid >> 6;
  const int n5 = lane & 31, hh = lane >> 5;
  const int bh = blockIdx.x, qb_ = 15 - (int)blockIdx.y;
  const int b = bh >> 4, h = bh & 15;
  const int q0 = qb_ * 128;
  const f16* qP = qB + (bh * 2048) * 64;
  const f16* kP = kB + (bh * 2048) * 64;
  const f16* vP = vB + (bh * 2048) * 64;

  const float slope2 = __builtin_amdgcn_exp2f(-0.5f * (float)(h + 1)) * LOG2E;
  const int qg = q0 + w * 32 + n5;              // this lane's q row (C col)
  const int qlast = q0 + w * 32 + 31;           // wave's last q row
  const int wdiag = ((q0 + w * 32) >> 6) << 6;  // 64-half holding wave's diag

  f16x8 qF[4];  // B-operand: B[k = ks*16 + hh*8 + j][n = qg]
#pragma unroll
  for (int ks = 0; ks < 4; ks++)
    qF[ks] = *(const f16x8*)(qP + qg * 64 + ks * 16 + hh * 8);

  f32x16 cinit, ot0, ot1;
#pragma unroll
  for (int i = 0; i < 16; i++) { cinit[i] = -8.0f; ot0[i] = 0.f; ot1[i] = 0.f; }
  float lsum = 0.0f;

  // K staging: thread -> rows {kr, kr+64}, col segs {kc, kc+32}; row permuted.
  const int kr = tid >> 2, kc = (tid & 3) * 8;
  const int pp = kr & 31;
  const int mperm = (pp & 3) + 16 * ((pp >> 2) & 1) + 4 * ((pp >> 3) & 1) + 8 * ((pp >> 4) & 1);
  const int lkr = (kr & 32) + mperm;
  // V staging: kv pair vp, d segs {vd0, vd0+32}; transpose to lV[d][kv].
  const int vp = (tid & 63) * 2, vd0 = (tid >> 6) * 8;

  f16x8 kA0, kA1, kB0, kB1, vA0, vA1, vB0, vB1;
  kA0 = *(const f16x8*)(kP + kr * 64 + kc);
  kA1 = *(const f16x8*)(kP + kr * 64 + kc + 32);
  kB0 = *(const f16x8*)(kP + (64 + kr) * 64 + kc);
  kB1 = *(const f16x8*)(kP + (64 + kr) * 64 + kc + 32);
  vA0 = *(const f16x8*)(vP + vp * 64 + vd0);
  vA1 = *(const f16x8*)(vP + (vp + 1) * 64 + vd0);
  vB0 = *(const f16x8*)(vP + vp * 64 + vd0 + 32);
  vB1 = *(const f16x8*)(vP + (vp + 1) * 64 + vd0 + 32);

  const int nstage = qb_ + 1;
  for (int stg = 0; stg < nstage; stg++) {
    const int kv0 = stg << 7;
    __syncthreads();
    *(f16x8*)(lK + lkr * LDA + kc) = kA0;
    *(f16x8*)(lK + lkr * LDA + kc + 32) = kA1;
    *(f16x8*)(lK + (64 + lkr) * LDA + kc) = kB0;
    *(f16x8*)(lK + (64 + lkr) * LDA + kc + 32) = kB1;
#pragma unroll
    for (int j = 0; j < 8; j++) {
      f16x2 t0; t0[0] = vA0[j]; t0[1] = vA1[j];
      *(f16x2*)(lV + (vd0 + j) * LDV + vp) = t0;
      f16x2 t1; t1[0] = vB0[j]; t1[1] = vB1[j];
      *(f16x2*)(lV + (vd0 + 32 + j) * LDV + vp) = t1;
    }
    __syncthreads();
    if (stg + 1 < nstage) {
      const int kn = kv0 + 128;
      kA0 = *(const f16x8*)(kP + (kn + kr) * 64 + kc);
      kA1 = *(const f16x8*)(kP + (kn + kr) * 64 + kc + 32);
      kB0 = *(const f16x8*)(kP + (kn + 64 + kr) * 64 + kc);
      kB1 = *(const f16x8*)(kP + (kn + 64 + kr) * 64 + kc + 32);
      vA0 = *(const f16x8*)(vP + (kn + vp) * 64 + vd0);
      vA1 = *(const f16x8*)(vP + (kn + vp + 1) * 64 + vd0);
      vB0 = *(const f16x8*)(vP + (kn + vp) * 64 + vd0 + 32);
      vB1 = *(const f16x8*)(vP + (kn + vp + 1) * 64 + vd0 + 32);
    }
#pragma unroll
    for (int half = 0; half < 2; half++) {
      const int kvh = kv0 + half * 64;
      if (kvh > wdiag) break;                    // wave-uniform
      const bool act1 = (kvh + 32 <= qlast);     // upper 32-kv tile live?
      const bool needmask = (kvh == wdiag);
      // S^T = K.Q^T, C-init = -8 (static max)
      f32x16 s0 = cinit, s1 = cinit;
#pragma unroll
      for (int ks = 0; ks < 4; ks++) {
        f16x8 kf = *(const f16x8*)(lK + (half * 64 + n5) * LDA + ks * 16 + hh * 8);
        s0 = __builtin_amdgcn_mfma_f32_32x32x16_f16(kf, qF[ks], s0, 0, 0, 0);
      }
      if (act1) {
#pragma unroll
        for (int ks = 0; ks < 4; ks++) {
          f16x8 kf = *(const f16x8*)(lK + (half * 64 + 32 + n5) * LDA + ks * 16 + hh * 8);
          s1 = __builtin_amdgcn_mfma_f32_32x32x16_f16(kf, qF[ks], s1, 0, 0, 0);
        }
      }
      // bias + mask + exp2. Element (reg=t+4u, hh) = physical kv offset
      // CR + 8*hh within its 32-tile, CR = 16*(u&1) + 4*(u>>1) + t.
      f16x8 pf00, pf01, pf10, pf11;
      {
        const int dQ = qg - kvh - 8 * hh;
        const float base0 = -slope2 * (float)dQ;
        float ev[16];
#pragma unroll
        for (int u = 0; u < 4; u++)
#pragma unroll
          for (int t = 0; t < 4; t++) {
            const int reg = t + 4 * u;
            const int CR = 16 * (u & 1) + 4 * (u >> 1) + t;
            float val = s0[reg] + fmaf(slope2, (float)CR, base0);
            if (needmask) val = (dQ >= CR) ? val : -1e30f;
            float e = __builtin_amdgcn_exp2f(val);
            lsum += e;
            ev[reg] = e;
          }
        pf00 = mkp(ev, 0); pf01 = mkp(ev, 1);
        if (act1) {
          const int dQ1 = dQ - 32;
          const float base1 = -slope2 * (float)dQ1;
          float ev1[16];
#pragma unroll
          for (int u = 0; u < 4; u++)
#pragma unroll
            for (int t = 0; t < 4; t++) {
              const int reg = t + 4 * u;
              const int CR = 16 * (u & 1) + 4 * (u >> 1) + t;
              float val = s1[reg] + fmaf(slope2, (float)CR, base1);
              if (needmask) val = (dQ1 >= CR) ? val : -1e30f;
              float e = __builtin_amdgcn_exp2f(val);
              lsum += e;
              ev1[reg] = e;
            }
          pf10 = mkp(ev1, 0); pf11 = mkp(ev1, 1);
        }
      }
      // O^T += V^T . P^T  (A = V^T b128 reads, contiguous physical kv)
#pragma unroll
      for (int p = 0; p < 2; p++) {
        f16x8 vf0 = *(const f16x8*)(lV + n5 * LDV + half * 64 + p * 16 + hh * 8);
        f16x8 vf1 = *(const f16x8*)(lV + (32 + n5) * LDV + half * 64 + p * 16 + hh * 8);
        f16x8 pf = p ? pf01 : pf00;
        ot0 = __builtin_amdgcn_mfma_f32_32x32x16_f16(vf0, pf, ot0, 0, 0, 0);
        ot1 = __builtin_amdgcn_mfma_f32_32x32x16_f16(vf1, pf, ot1, 0, 0, 0);
      }
      if (act1) {
#pragma unroll
        for (int p = 0; p < 2; p++) {
          f16x8 vf0 = *(const f16x8*)(lV + n5 * LDV + half * 64 + 32 + p * 16 + hh * 8);
          f16x8 vf1 = *(const f16x8*)(lV + (32 + n5) * LDV + half * 64 + 32 + p * 16 + hh * 8);
          f16x8 pf = p ? pf11 : pf10;
          ot0 = __builtin_amdgcn_mfma_f32_32x32x16_f16(vf0, pf, ot0, 0, 0, 0);
          ot1 = __builtin_amdgcn_mfma_f32_32x32x16_f16(vf1, pf, ot1, 0, 0, 0);
        }
      }
    }
  }

  // l per q-col lives split across hh halves only
  lsum += __shfl_xor(lsum, 32);
  const float inv = 1.0f / lsum;

  // epilogue: O^T regs -> LDS [q][d] -> coalesced f16x8 stores
  __syncthreads();
  f16* OT = lK + w * (32 * LDA);
#pragma unroll
  for (int dt = 0; dt < 2; dt++)
#pragma unroll
    for (int u = 0; u < 4; u++) {
      f16x4 o4;
#pragma unroll
      for (int t = 0; t < 4; t++) {
        float v = (dt ? ot1[t + 4 * u] : ot0[t + 4 * u]) * inv;
        o4[t] = (f16)v;
      }
      // d = dt*32 + 8u + 4hh + t
      *(f16x4*)(OT + n5 * LDA + dt * 32 + 8 * u + 4 * hh) = o4;
    }
  __syncthreads();
  const int row = lane >> 1, hr = lane & 1;
  const f16* OR = lK + w * (32 * LDA) + row * LDA + hr * 32;
  f16* dst = att + (b * 2048 + q0 + w * 32 + row) * 1024 + h * 64 + hr * 32;
#pragma unroll
  for (int j = 0; j < 4; j++)
    *(f16x8*)(dst + j * 8) = *(const f16x8*)(OR + j * 8);
}

// ---------------------------------------------------------- output projection
__global__ __launch_bounds__(256) void out_proj(
    const f16* __restrict__ att, const f16* __restrict__ wo16,
    float* __restrict__ out) {
  __shared__ __align__(16) f16 lA[2 * 128 * LDK];
  __shared__ __align__(16) f16 lW[2 * 128 * LDK];
  const int m0 = blockIdx.x * 128, n0 = blockIdx.y * 128;
  f32x4 acc[4][4];
  const f32x4 zero = {0.f, 0.f, 0.f, 0.f};
#pragma unroll
  for (int i = 0; i < 4; i++)
#pragma unroll
    for (int j = 0; j < 4; j++) acc[i][j] = zero;
  gemm_core(att, wo16, m0, n0, lA, lW, acc);

  const int tid = threadIdx.x, lane = tid & 63, w = tid >> 6;
  const int wm = w & 1, wn = w >> 1, q = lane & 15, quad = lane >> 4;
#pragma unroll
  for (int mt = 0; mt < 4; mt++)
#pragma unroll
    for (int nt = 0; nt < 4; nt++) {
      int n = n0 + wn * 64 + nt * 16 + q;
#pragma unroll
      for (int r = 0; r < 4; r++) {
        int mm = m0 + wm * 64 + mt * 16 + quad * 4 + r;
        out[mm * 1024 + n] = acc[mt][nt][r];
      }
    }
}

// ------------------------------------------------------------------- launch
extern "C" void kernel_launch(void* const* d_in, const int* in_sizes, int n_in,
                              void* d_out, int out_size, void* d_ws, size_t ws_size,
                              hipStream_t stream) {
  const float* x  = (const float*)d_in[0];
  const float* Wq = (const float*)d_in[1];
  const float* Wk = (const float*)d_in[2];
  const float* Wv = (const float*)d_in[3];
  const float* Wo = (const float*)d_in[4];
  char* ws = (char*)d_ws;
  const size_t MB = 1024 * 1024;
  f16* x16  = (f16*)(ws);             // 8 MB; dead after qkv -> reused as att
  f16* qb   = (f16*)(ws + 8 * MB);    // (B,H,T,D) f16, 8 MB each
  f16* kb   = (f16*)(ws + 16 * MB);
  f16* vb   = (f16*)(ws + 24 * MB);
  f16* wq16 = (f16*)(ws + 32 * MB);   // 2 MB each
  f16* wk16 = (f16*)(ws + 34 * MB);
  f16* wv16 = (f16*)(ws + 36 * MB);
  f16* wo16 = (f16*)(ws + 38 * MB);   // total 40 MB
  f16* att  = x16;                    // overlay

  cvt_f32_f16<<<dim3(2048, 5), 256, 0, stream>>>(x, Wq, Wk, Wv, Wo,
                                                 x16, wq16, wk16, wv16, wo16);
  qkv_proj<<<dim3(32, 8, 3), 256, 0, stream>>>(x16, wq16, wk16, wv16,
                                               qb, kb, vb, 0.125f * LOG2E);
  attn<<<dim3(32, 16), 256, 0, stream>>>(qb, kb, vb, att);
  out_proj<<<dim3(32, 8), 256, 0, stream>>>(att, wo16, (float*)d_out);
}